// Round 10
// baseline (210.787 us; speedup 1.0000x reference)
//
#include <hip/hip_runtime.h>

// GCN 2-layer encoder for MI355X (gfx950) — round 10.
// r9 post-mortem: fill stuck ~45-66us across ALL variants; signature is
// WRITE_SIZE 40-65MB for <5MB payload = random-store line re-dirty across
// 8 non-coherent XCD L2s. r10: 8-sharded CSR — edges chunked by position,
// fill block chunk = blockIdx%8 (matches round-robin block->XCD) so each
// ~150KB csr region is written by ONE XCD and stays L2-resident; entries
// are ushort (N<65536) -> csr total 1.2MB. Gathers read 8 mini-segments
// per node. MFMA GEMMs (LDS-free, pre-split bf16 hi/lo weights) kept.
//
// Pipeline (8 dispatches):
//   k_init(zero indeg8 || split W1,W2) -> k_count8 -> k_scan1 ->
//   k_scan3(apply+cursor || dinv) -> k_fill_gemm1(fill || mfma-gemm1) ->
//   k_gather_relu -> k_gemm2_mfma -> k_gather64

constexpr int IN_CH  = 128;
constexpr int HID    = 128;
constexpr int OUT_CH = 64;
constexpr int SCAN_CHUNK = 4096;
constexpr int NCHUNK = 8;

using short8v = __attribute__((ext_vector_type(8))) short;
using f32x4v  = __attribute__((ext_vector_type(4))) float;

__device__ __forceinline__ unsigned short f2bf_rne(float f) {
    unsigned int u = __float_as_uint(f);
    u += 0x7FFFu + ((u >> 16) & 1u);
    return (unsigned short)(u >> 16);
}
__device__ __forceinline__ float bf2f(unsigned short h) {
    return __uint_as_float((unsigned int)h << 16);
}

__device__ __forceinline__ bool probe_is64(const int* __restrict__ ei) {
    const int v = ei[2 * (threadIdx.x & 63) + 1];
    return __ballot(v != 0) == 0ull;
}

// Load up to 4 consecutive indices from half `hb` (0=src, E=dst) at e0.
__device__ __forceinline__ void load_idx4(const int* __restrict__ ei, bool is64,
                                          long long hb, int e0, int n, int* out) {
    const long long p = hb + e0;
    if (is64) {
        if (n == 4 && ((p & 1) == 0)) {
            const int4 a = *reinterpret_cast<const int4*>(ei + 2 * p);
            const int4 b = *reinterpret_cast<const int4*>(ei + 2 * p + 4);
            out[0] = a.x; out[1] = a.z; out[2] = b.x; out[3] = b.z;
        } else {
            for (int j = 0; j < n; ++j) out[j] = ei[2 * (p + j)];
        }
    } else {
        if (n == 4 && ((p & 3) == 0)) {
            const int4 a = *reinterpret_cast<const int4*>(ei + p);
            out[0] = a.x; out[1] = a.y; out[2] = a.z; out[3] = a.w;
        } else {
            for (int j = 0; j < n; ++j) out[j] = ei[p + j];
        }
    }
}

// blocks 0..63: zero indeg8 (8N ints). 64..79: split W1. 80..87: split W2.
__global__ __launch_bounds__(256) void k_init(int* __restrict__ indeg8, int M8,
                                              const float* __restrict__ W1,
                                              const float* __restrict__ W2,
                                              unsigned short* __restrict__ w1th,
                                              unsigned short* __restrict__ w1tl,
                                              unsigned short* __restrict__ w2th,
                                              unsigned short* __restrict__ w2tl) {
    const int b = blockIdx.x;
    if (b < 64) {
        const int i = b * 256 + threadIdx.x;
        const int n4 = M8 / 4;
        for (int j = i; j < n4; j += 64 * 256)
            reinterpret_cast<int4*>(indeg8)[j] = make_int4(0, 0, 0, 0);
        const int tail = n4 * 4 + i;
        if (tail < M8) indeg8[tail] = 0;
    } else if (b < 80) {
        const int i = (b - 64) * 1024 + threadIdx.x * 4;
        const int n = i >> 7, k = i & 127;
#pragma unroll
        for (int j = 0; j < 4; ++j) {
            const float f = W1[(size_t)(k + j) * HID + n];
            const unsigned short h = f2bf_rne(f);
            w1th[n * 128 + k + j] = h;
            w1tl[n * 128 + k + j] = f2bf_rne(f - bf2f(h));
        }
    } else {
        const int i = (b - 80) * 1024 + threadIdx.x * 4;
        const int n = i >> 7, k = i & 127;
#pragma unroll
        for (int j = 0; j < 4; ++j) {
            const float f = W2[(size_t)(k + j) * OUT_CH + n];
            const unsigned short h = f2bf_rne(f);
            w2th[n * 128 + k + j] = h;
            w2tl[n * 128 + k + j] = f2bf_rne(f - bf2f(h));
        }
    }
}

// indeg8[c][d]++ where c = e / CH (position-chunk of the edge).
__global__ void k_count8(const int* __restrict__ ei, int* __restrict__ indeg8,
                         int E, int CH, int N) {
    const bool is64 = probe_is64(ei);
    const int idx    = blockIdx.x * blockDim.x + threadIdx.x;
    const int stride = gridDim.x * blockDim.x;
    for (int e0 = idx * 4; e0 < E; e0 += stride * 4) {
        const int n = min(4, E - e0);
        int d[4];
        load_idx4(ei, is64, (long long)E, e0, n, d);
        const int c0 = e0 / CH;
        const int c1 = (e0 + n - 1) / CH;
        if (c0 == c1) {
            int* base = indeg8 + c0 * N;
            for (int j = 0; j < n; ++j) atomicAdd(&base[d[j]], 1);
        } else {
            for (int j = 0; j < n; ++j)
                atomicAdd(&indeg8[((e0 + j) / CH) * N + d[j]], 1);
        }
    }
}

// Exclusive scan of indeg8 (flat, M8 elems) -> row_ptr8; partials[b] = total.
__global__ __launch_bounds__(256) void k_scan1(const int* __restrict__ indeg8,
                                               int* __restrict__ row_ptr8,
                                               int* __restrict__ partials, int M8) {
    const int t    = threadIdx.x;
    const int base = blockIdx.x * SCAN_CHUNK + t * 16;
    int v[16];
    if (base + 15 < M8) {
        const int4* p = reinterpret_cast<const int4*>(indeg8 + base);
#pragma unroll
        for (int q = 0; q < 4; ++q) {
            const int4 a = p[q];
            v[q * 4 + 0] = a.x; v[q * 4 + 1] = a.y;
            v[q * 4 + 2] = a.z; v[q * 4 + 3] = a.w;
        }
    } else {
#pragma unroll
        for (int j = 0; j < 16; ++j)
            v[j] = (base + j < M8) ? indeg8[base + j] : 0;
    }

    int sum = 0;
#pragma unroll
    for (int j = 0; j < 16; ++j) { const int tv = v[j]; v[j] = sum; sum += tv; }

    int incl = sum;
#pragma unroll
    for (int off = 1; off < 64; off <<= 1) {
        int tt = __shfl_up(incl, off, 64);
        if ((t & 63) >= off) incl += tt;
    }
    __shared__ int wsum[4];
    if ((t & 63) == 63) wsum[t >> 6] = incl;
    __syncthreads();
    int woff = 0;
#pragma unroll
    for (int w = 0; w < 4; ++w) woff += (w < (t >> 6)) ? wsum[w] : 0;
    const int texcl = woff + incl - sum;

#pragma unroll
    for (int j = 0; j < 16; ++j)
        if (base + j < M8) row_ptr8[base + j] = texcl + v[j];
    if (t == 255) partials[blockIdx.x] = woff + incl;
}

// blocks [0,nblk): apply partial offsets, write cursor8; last writes rp8[M8].
// blocks [nblk, nblk+dinvB): dinv[n] = rsqrt(1 + sum_c indeg8[c][n]).
__global__ __launch_bounds__(256) void k_scan3(const int* __restrict__ partials,
                                               int* __restrict__ row_ptr8,
                                               int* __restrict__ cursor8,
                                               const int* __restrict__ indeg8,
                                               float* __restrict__ dinv,
                                               int M8, int nblk, int N) {
    if ((int)blockIdx.x >= nblk) {
        const int n = ((int)blockIdx.x - nblk) * 256 + threadIdx.x;
        if (n < N) {
            int deg = 1;
#pragma unroll
            for (int c = 0; c < NCHUNK; ++c) deg += indeg8[c * N + n];
            dinv[n] = rsqrtf((float)deg);
        }
        return;
    }
    int off = 0;
    for (int w = 0; w < (int)blockIdx.x; ++w) off += partials[w];

    const int base = blockIdx.x * SCAN_CHUNK + threadIdx.x * 16;
    if (base + 15 < M8) {
        int4* rp = reinterpret_cast<int4*>(row_ptr8 + base);
        int4* cp = reinterpret_cast<int4*>(cursor8 + base);
#pragma unroll
        for (int q = 0; q < 4; ++q) {
            int4 a = rp[q];
            a.x += off; a.y += off; a.z += off; a.w += off;
            rp[q] = a; cp[q] = a;
        }
    } else {
#pragma unroll
        for (int j = 0; j < 16; ++j) {
            const int i = base + j;
            if (i < M8) { const int r = row_ptr8[i] + off; row_ptr8[i] = r; cursor8[i] = r; }
        }
    }
    if ((int)blockIdx.x == nblk - 1 && threadIdx.x == 255)
        row_ptr8[M8] = off + partials[nblk - 1];
}

// MFMA GEMM1, LDS-free (r9, verified): h1b = x @ W1, split-precision.
__device__ __forceinline__ void gemm1_mfma(const float* __restrict__ X,
                                           const unsigned short* __restrict__ w1th,
                                           const unsigned short* __restrict__ w1tl,
                                           unsigned short* __restrict__ Y,
                                           int M, int blk) {
    const int tid = threadIdx.x;
    const int wv  = tid >> 6;
    const int ln  = tid & 63;
    const int m16 = ln & 15;
    const int g   = ln >> 4;
    const int arow = blk * 64 + wv * 16 + m16;

    f32x4v acc[8];
#pragma unroll
    for (int n = 0; n < 8; ++n) acc[n] = {0.f, 0.f, 0.f, 0.f};

#pragma unroll
    for (int k0 = 0; k0 < 128; k0 += 32) {
        short8v ah, al;
        if (arow < M) {
            const float4 a0 = *reinterpret_cast<const float4*>(
                X + (size_t)arow * 128 + k0 + g * 8);
            const float4 a1 = *reinterpret_cast<const float4*>(
                X + (size_t)arow * 128 + k0 + g * 8 + 4);
            const float f[8] = {a0.x, a0.y, a0.z, a0.w, a1.x, a1.y, a1.z, a1.w};
#pragma unroll
            for (int e = 0; e < 8; ++e) {
                const unsigned short h = f2bf_rne(f[e]);
                ah[e] = (short)h;
                al[e] = (short)f2bf_rne(f[e] - bf2f(h));
            }
        } else {
#pragma unroll
            for (int e = 0; e < 8; ++e) { ah[e] = 0; al[e] = 0; }
        }

#pragma unroll
        for (int n = 0; n < 8; ++n) {
            const short8v bh = *reinterpret_cast<const short8v*>(
                w1th + (n * 16 + m16) * 128 + k0 + g * 8);
            const short8v bl = *reinterpret_cast<const short8v*>(
                w1tl + (n * 16 + m16) * 128 + k0 + g * 8);
            acc[n] = __builtin_amdgcn_mfma_f32_16x16x32_bf16(ah, bh, acc[n], 0, 0, 0);
            acc[n] = __builtin_amdgcn_mfma_f32_16x16x32_bf16(al, bh, acc[n], 0, 0, 0);
            acc[n] = __builtin_amdgcn_mfma_f32_16x16x32_bf16(ah, bl, acc[n], 0, 0, 0);
        }
    }

#pragma unroll
    for (int r = 0; r < 4; ++r) {
        const int orow = blk * 64 + wv * 16 + g * 4 + r;
        if (orow < M) {
#pragma unroll
            for (int n = 0; n < 8; ++n)
                Y[(size_t)orow * 128 + n * 16 + m16] = f2bf_rne(acc[n][r]);
        }
    }
}

// Dual-role: blocks [0, fillBlocks) fill chunk c = blockIdx%8 (XCD-local
// csr region); the rest run MFMA gemm1.
__global__ __launch_bounds__(256) void k_fill_gemm1(
    const float* __restrict__ X, const unsigned short* __restrict__ w1th,
    const unsigned short* __restrict__ w1tl, unsigned short* __restrict__ Y,
    int M, int fillBlocks, const int* __restrict__ ei,
    int* __restrict__ cursor8, unsigned short* __restrict__ csr16,
    int E, int CH, int N) {
    if ((int)blockIdx.x >= fillBlocks) {
        gemm1_mfma(X, w1th, w1tl, Y, M, blockIdx.x - fillBlocks);
        return;
    }
    const bool is64 = probe_is64(ei);
    const int c     = blockIdx.x & (NCHUNK - 1);
    const int beg   = c * CH;
    const int end   = min(E, beg + CH);
    const int bpc   = fillBlocks / NCHUNK;            // blocks per chunk
    const int lt    = ((int)blockIdx.x >> 3) * 256 + threadIdx.x;
    const int nthr  = bpc * 256;
    int* cur        = cursor8 + c * N;
    for (int e0 = beg + lt * 4; e0 < end; e0 += nthr * 4) {
        const int n = min(4, end - e0);
        int s[4], d[4];
        load_idx4(ei, is64, 0,            e0, n, s);
        load_idx4(ei, is64, (long long)E, e0, n, d);
        int pos[4];
        for (int j = 0; j < n; ++j) pos[j] = atomicAdd(&cur[d[j]], 1);
        for (int j = 0; j < n; ++j) csr16[pos[j]] = (unsigned short)s[j];
    }
}

// MFMA GEMM2, LDS-free (r9): h2b = aggb @ W2, W2 split.
__global__ __launch_bounds__(256) void k_gemm2_mfma(
    const unsigned short* __restrict__ Xb, const unsigned short* __restrict__ w2th,
    const unsigned short* __restrict__ w2tl, unsigned short* __restrict__ Y, int M) {
    const int tid = threadIdx.x;
    const int wv  = tid >> 6;
    const int ln  = tid & 63;
    const int m16 = ln & 15;
    const int g   = ln >> 4;
    const int arow = blockIdx.x * 64 + wv * 16 + m16;

    f32x4v acc[4];
#pragma unroll
    for (int n = 0; n < 4; ++n) acc[n] = {0.f, 0.f, 0.f, 0.f};

#pragma unroll
    for (int k0 = 0; k0 < 128; k0 += 32) {
        short8v a;
        if (arow < M) {
            a = *reinterpret_cast<const short8v*>(Xb + (size_t)arow * 128 + k0 + g * 8);
        } else {
#pragma unroll
            for (int e = 0; e < 8; ++e) a[e] = 0;
        }
#pragma unroll
        for (int n = 0; n < 4; ++n) {
            const short8v bh = *reinterpret_cast<const short8v*>(
                w2th + (n * 16 + m16) * 128 + k0 + g * 8);
            const short8v bl = *reinterpret_cast<const short8v*>(
                w2tl + (n * 16 + m16) * 128 + k0 + g * 8);
            acc[n] = __builtin_amdgcn_mfma_f32_16x16x32_bf16(a, bh, acc[n], 0, 0, 0);
            acc[n] = __builtin_amdgcn_mfma_f32_16x16x32_bf16(a, bl, acc[n], 0, 0, 0);
        }
    }

#pragma unroll
    for (int r = 0; r < 4; ++r) {
        const int orow = blockIdx.x * 64 + wv * 16 + g * 4 + r;
        if (orow < M) {
#pragma unroll
            for (int n = 0; n < 4; ++n)
                Y[(size_t)orow * 64 + n * 16 + m16] = f2bf_rne(acc[n][r]);
        }
    }
}

// aggb[n](bf16) = relu(b1 + h[n]*dinv[n]^2 + sum_{c,e} h[s]*dinv[s]*dinv[n])
__global__ __launch_bounds__(256) void k_gather_relu(
    const unsigned short* __restrict__ h, const int* __restrict__ rp8,
    const unsigned short* __restrict__ csr16, const float* __restrict__ dinv,
    const float* __restrict__ b, unsigned short* __restrict__ aggb, int N) {
    constexpr int LPN = HID / 4;   // 32
    const int tid  = blockIdx.x * blockDim.x + threadIdx.x;
    const int node = tid / LPN;
    const int lane = tid % LPN;
    if (node >= N) return;

    const float dn = dinv[node];
    float4 acc = reinterpret_cast<const float4*>(b)[lane];
    {
        const float w = dn * dn;
        const ushort4 v = *reinterpret_cast<const ushort4*>(h + (size_t)node * HID + lane * 4);
        acc.x = fmaf(bf2f(v.x), w, acc.x); acc.y = fmaf(bf2f(v.y), w, acc.y);
        acc.z = fmaf(bf2f(v.z), w, acc.z); acc.w = fmaf(bf2f(v.w), w, acc.w);
    }

#pragma unroll
    for (int c = 0; c < NCHUNK; ++c) {
        const int e1 = rp8[c * N + node + 1];
        int e = rp8[c * N + node];
        for (; e + 1 < e1; e += 2) {
            const int s0 = csr16[e];
            const int s1 = csr16[e + 1];
            const float w0 = dinv[s0] * dn;
            const float w1 = dinv[s1] * dn;
            const ushort4 v0 = *reinterpret_cast<const ushort4*>(h + (size_t)s0 * HID + lane * 4);
            const ushort4 v1 = *reinterpret_cast<const ushort4*>(h + (size_t)s1 * HID + lane * 4);
            acc.x = fmaf(bf2f(v0.x), w0, acc.x); acc.y = fmaf(bf2f(v0.y), w0, acc.y);
            acc.z = fmaf(bf2f(v0.z), w0, acc.z); acc.w = fmaf(bf2f(v0.w), w0, acc.w);
            acc.x = fmaf(bf2f(v1.x), w1, acc.x); acc.y = fmaf(bf2f(v1.y), w1, acc.y);
            acc.z = fmaf(bf2f(v1.z), w1, acc.z); acc.w = fmaf(bf2f(v1.w), w1, acc.w);
        }
        if (e < e1) {
            const int s0 = csr16[e];
            const float w0 = dinv[s0] * dn;
            const ushort4 v0 = *reinterpret_cast<const ushort4*>(h + (size_t)s0 * HID + lane * 4);
            acc.x = fmaf(bf2f(v0.x), w0, acc.x); acc.y = fmaf(bf2f(v0.y), w0, acc.y);
            acc.z = fmaf(bf2f(v0.z), w0, acc.z); acc.w = fmaf(bf2f(v0.w), w0, acc.w);
        }
    }

    ushort4 o;
    o.x = f2bf_rne(fmaxf(acc.x, 0.f));
    o.y = f2bf_rne(fmaxf(acc.y, 0.f));
    o.z = f2bf_rne(fmaxf(acc.z, 0.f));
    o.w = f2bf_rne(fmaxf(acc.w, 0.f));
    *reinterpret_cast<ushort4*>(aggb + (size_t)node * HID + lane * 4) = o;
}

// out[n](f32) = b2 + h[n]*dinv[n]^2 + sum_{c,e} h[s]*dinv[s]*dinv[n]
__global__ __launch_bounds__(256) void k_gather64(
    const unsigned short* __restrict__ h, const int* __restrict__ rp8,
    const unsigned short* __restrict__ csr16, const float* __restrict__ dinv,
    const float* __restrict__ b, float* __restrict__ out, int N) {
    constexpr int LPN = OUT_CH / 4;   // 16
    const int tid  = blockIdx.x * blockDim.x + threadIdx.x;
    const int node = tid / LPN;
    const int lane = tid % LPN;
    if (node >= N) return;

    const float dn = dinv[node];
    float4 acc = reinterpret_cast<const float4*>(b)[lane];
    {
        const float w = dn * dn;
        const ushort4 v = *reinterpret_cast<const ushort4*>(h + (size_t)node * OUT_CH + lane * 4);
        acc.x = fmaf(bf2f(v.x), w, acc.x); acc.y = fmaf(bf2f(v.y), w, acc.y);
        acc.z = fmaf(bf2f(v.z), w, acc.z); acc.w = fmaf(bf2f(v.w), w, acc.w);
    }

#pragma unroll
    for (int c = 0; c < NCHUNK; ++c) {
        const int e1 = rp8[c * N + node + 1];
        int e = rp8[c * N + node];
        for (; e + 1 < e1; e += 2) {
            const int s0 = csr16[e];
            const int s1 = csr16[e + 1];
            const float w0 = dinv[s0] * dn;
            const float w1 = dinv[s1] * dn;
            const ushort4 v0 = *reinterpret_cast<const ushort4*>(h + (size_t)s0 * OUT_CH + lane * 4);
            const ushort4 v1 = *reinterpret_cast<const ushort4*>(h + (size_t)s1 * OUT_CH + lane * 4);
            acc.x = fmaf(bf2f(v0.x), w0, acc.x); acc.y = fmaf(bf2f(v0.y), w0, acc.y);
            acc.z = fmaf(bf2f(v0.z), w0, acc.z); acc.w = fmaf(bf2f(v0.w), w0, acc.w);
            acc.x = fmaf(bf2f(v1.x), w1, acc.x); acc.y = fmaf(bf2f(v1.y), w1, acc.y);
            acc.z = fmaf(bf2f(v1.z), w1, acc.z); acc.w = fmaf(bf2f(v1.w), w1, acc.w);
        }
        if (e < e1) {
            const int s0 = csr16[e];
            const float w0 = dinv[s0] * dn;
            const ushort4 v0 = *reinterpret_cast<const ushort4*>(h + (size_t)s0 * OUT_CH + lane * 4);
            acc.x = fmaf(bf2f(v0.x), w0, acc.x); acc.y = fmaf(bf2f(v0.y), w0, acc.y);
            acc.z = fmaf(bf2f(v0.z), w0, acc.z); acc.w = fmaf(bf2f(v0.w), w0, acc.w);
        }
    }

    reinterpret_cast<float4*>(out + (size_t)node * OUT_CH)[lane] = acc;
}

extern "C" void kernel_launch(void* const* d_in, const int* in_sizes, int n_in,
                              void* d_out, int out_size, void* d_ws, size_t ws_size,
                              hipStream_t stream) {
    const float* x  = (const float*)d_in[0];
    const int*   ei = (const int*)d_in[1];
    const float* W1 = (const float*)d_in[2];
    const float* b1 = (const float*)d_in[3];
    const float* W2 = (const float*)d_in[4];
    const float* b2 = (const float*)d_in[5];
    float* out = (float*)d_out;

    const int N  = in_sizes[0] / IN_CH;     // 50000
    const int E  = in_sizes[1] / 2;         // 600000
    const int CH = (E + NCHUNK - 1) / NCHUNK;
    const int M8 = NCHUNK * N;
    const int NBLK8 = (M8 + SCAN_CHUNK - 1) / SCAN_CHUNK;   // 98
    const int DINVB = (N + 255) / 256;                       // 196

    char* wsb = (char*)d_ws;
    size_t off = 0;
    auto alloc = [&](size_t bytes) -> void* {
        void* p = wsb + off;
        off += (bytes + 255) & ~(size_t)255;
        return p;
    };
    int*   indeg8   = (int*)alloc((size_t)M8 * sizeof(int));
    int*   partials = (int*)alloc(128 * sizeof(int));
    float* dinv     = (float*)alloc((size_t)N * sizeof(float));
    int*   row_ptr8 = (int*)alloc(((size_t)M8 + 1) * sizeof(int));
    int*   cursor8  = (int*)alloc((size_t)M8 * sizeof(int));
    unsigned short* csr16 = (unsigned short*)alloc((size_t)E * sizeof(unsigned short));
    unsigned short* w1th = (unsigned short*)alloc(128 * 128 * sizeof(unsigned short));
    unsigned short* w1tl = (unsigned short*)alloc(128 * 128 * sizeof(unsigned short));
    unsigned short* w2th = (unsigned short*)alloc(64 * 128 * sizeof(unsigned short));
    unsigned short* w2tl = (unsigned short*)alloc(64 * 128 * sizeof(unsigned short));
    unsigned short* h1b  = (unsigned short*)alloc((size_t)N * HID * sizeof(unsigned short));
    unsigned short* aggb = (unsigned short*)alloc((size_t)N * HID * sizeof(unsigned short));
    unsigned short* h2b  = (unsigned short*)alloc((size_t)N * OUT_CH * sizeof(unsigned short));

    auto gs = [](long long n) { return (int)((n + 255) / 256); };

    k_init<<<88, 256, 0, stream>>>(indeg8, M8, W1, W2, w1th, w1tl, w2th, w2tl);
    k_count8<<<gs((E + 3) / 4), 256, 0, stream>>>(ei, indeg8, E, CH, N);
    k_scan1<<<NBLK8, 256, 0, stream>>>(indeg8, row_ptr8, partials, M8);
    k_scan3<<<NBLK8 + DINVB, 256, 0, stream>>>(partials, row_ptr8, cursor8,
                                               indeg8, dinv, M8, NBLK8, N);

    // fill (chunk = blockIdx%8, XCD-local csr region) || LDS-free MFMA gemm1
    const int fillBlocks = 512;
    const int gemmBlocks = (N + 63) / 64;   // 782
    k_fill_gemm1<<<fillBlocks + gemmBlocks, 256, 0, stream>>>(
        x, w1th, w1tl, h1b, N, fillBlocks, ei, cursor8, csr16, E, CH, N);

    k_gather_relu<<<gs((long long)N * (HID / 4)), 256, 0, stream>>>(
        h1b, row_ptr8, csr16, dinv, b1, aggb, N);

    k_gemm2_mfma<<<(N + 63) / 64, 256, 0, stream>>>(aggb, w2th, w2tl, h2b, N);

    k_gather64<<<gs((long long)N * (OUT_CH / 4)), 256, 0, stream>>>(
        h2b, row_ptr8, csr16, dinv, b2, out, N);
}

// Round 11
// 159.001 us; speedup vs baseline: 1.3257x; 1.3257x over previous
//
#include <hip/hip_runtime.h>

// GCN 2-layer encoder for MI355X (gfx950) — round 11.
// r8-r10 post-mortem: fill pinned at 42-66us across ILP/grid/sharding with
// NOTHING saturated -> suspect the atomicAdd-WITH-RETURN round trip (store
// depends on it). r11: atomic-free fill. k_count already computes each
// edge's rank within its dst segment — store it (coalesced int4). Fill is
// then pure streaming: csr[row_ptr[d]+rank[e]] = {src, dinv[src]}.
// Everything else reverted to best-known: r7 single-segment int2 gathers,
// r9 LDS-free MFMA gemms (0 bank conflicts), split weights in k_init.
//
// Pipeline (9 dispatches):
//   k_init(zero indeg || split W1,W2) -> k_count_rank -> k_scan1(+dinv)
//   -> k_scan3 -> k_fill_gemm1(streaming fill || mfma-gemm1)
//   -> k_gather_relu -> k_gemm2_mfma -> k_gather64

constexpr int IN_CH  = 128;
constexpr int HID    = 128;
constexpr int OUT_CH = 64;
constexpr int SCAN_CHUNK = 4096;

using short8v = __attribute__((ext_vector_type(8))) short;
using f32x4v  = __attribute__((ext_vector_type(4))) float;

__device__ __forceinline__ unsigned short f2bf_rne(float f) {
    unsigned int u = __float_as_uint(f);
    u += 0x7FFFu + ((u >> 16) & 1u);
    return (unsigned short)(u >> 16);
}
__device__ __forceinline__ float bf2f(unsigned short h) {
    return __uint_as_float((unsigned int)h << 16);
}

__device__ __forceinline__ bool probe_is64(const int* __restrict__ ei) {
    const int v = ei[2 * (threadIdx.x & 63) + 1];
    return __ballot(v != 0) == 0ull;
}

// Load up to 4 consecutive indices from half `hb` (0=src, E=dst) at e0.
__device__ __forceinline__ void load_idx4(const int* __restrict__ ei, bool is64,
                                          long long hb, int e0, int n, int* out) {
    const long long p = hb + e0;
    if (is64) {
        if (n == 4 && ((p & 1) == 0)) {
            const int4 a = *reinterpret_cast<const int4*>(ei + 2 * p);
            const int4 b = *reinterpret_cast<const int4*>(ei + 2 * p + 4);
            out[0] = a.x; out[1] = a.z; out[2] = b.x; out[3] = b.z;
        } else {
            for (int j = 0; j < n; ++j) out[j] = ei[2 * (p + j)];
        }
    } else {
        if (n == 4 && ((p & 3) == 0)) {
            const int4 a = *reinterpret_cast<const int4*>(ei + p);
            out[0] = a.x; out[1] = a.y; out[2] = a.z; out[3] = a.w;
        } else {
            for (int j = 0; j < n; ++j) out[j] = ei[p + j];
        }
    }
}

// blocks 0..63: zero indeg. 64..79: split W1 (bf16 hi/lo, transposed [n][k]).
// 80..87: split W2.
__global__ __launch_bounds__(256) void k_init(int* __restrict__ indeg, int N,
                                              const float* __restrict__ W1,
                                              const float* __restrict__ W2,
                                              unsigned short* __restrict__ w1th,
                                              unsigned short* __restrict__ w1tl,
                                              unsigned short* __restrict__ w2th,
                                              unsigned short* __restrict__ w2tl) {
    const int b = blockIdx.x;
    if (b < 64) {
        const int i = b * 256 + threadIdx.x;
        const int n4 = N / 4;
        for (int j = i; j < n4; j += 64 * 256)
            reinterpret_cast<int4*>(indeg)[j] = make_int4(0, 0, 0, 0);
        const int tail = n4 * 4 + i;
        if (tail < N) indeg[tail] = 0;
    } else if (b < 80) {
        const int i = (b - 64) * 1024 + threadIdx.x * 4;
        const int n = i >> 7, k = i & 127;
#pragma unroll
        for (int j = 0; j < 4; ++j) {
            const float f = W1[(size_t)(k + j) * HID + n];
            const unsigned short h = f2bf_rne(f);
            w1th[n * 128 + k + j] = h;
            w1tl[n * 128 + k + j] = f2bf_rne(f - bf2f(h));
        }
    } else {
        const int i = (b - 80) * 1024 + threadIdx.x * 4;
        const int n = i >> 7, k = i & 127;
#pragma unroll
        for (int j = 0; j < 4; ++j) {
            const float f = W2[(size_t)(k + j) * OUT_CH + n];
            const unsigned short h = f2bf_rne(f);
            w2th[n * 128 + k + j] = h;
            w2tl[n * 128 + k + j] = f2bf_rne(f - bf2f(h));
        }
    }
}

// rank[e] = atomicAdd(&indeg[dst[e]], 1)  — rank stored coalesced (int4).
__global__ void k_count_rank(const int* __restrict__ ei, int* __restrict__ indeg,
                             int* __restrict__ rank, int E) {
    const bool is64 = probe_is64(ei);
    const int idx    = blockIdx.x * blockDim.x + threadIdx.x;
    const int stride = gridDim.x * blockDim.x;
    for (int e0 = idx * 4; e0 < E; e0 += stride * 4) {
        const int n = min(4, E - e0);
        int d[4];
        load_idx4(ei, is64, (long long)E, e0, n, d);
        if (n == 4) {
            int4 r;
            r.x = atomicAdd(&indeg[d[0]], 1);
            r.y = atomicAdd(&indeg[d[1]], 1);
            r.z = atomicAdd(&indeg[d[2]], 1);
            r.w = atomicAdd(&indeg[d[3]], 1);
            *reinterpret_cast<int4*>(rank + e0) = r;
        } else {
            for (int j = 0; j < n; ++j)
                rank[e0 + j] = atomicAdd(&indeg[d[j]], 1);
        }
    }
}

// Exclusive scan of indeg -> row_ptr; dinv = rsqrt(indeg+1); partials.
__global__ __launch_bounds__(256) void k_scan1(const int* __restrict__ indeg,
                                               int* __restrict__ row_ptr,
                                               float* __restrict__ dinv,
                                               int* __restrict__ partials, int N) {
    const int t    = threadIdx.x;
    const int base = blockIdx.x * SCAN_CHUNK + t * 16;
    int v[16];
    if (base + 15 < N) {
        const int4* p = reinterpret_cast<const int4*>(indeg + base);
#pragma unroll
        for (int q = 0; q < 4; ++q) {
            const int4 a = p[q];
            v[q * 4 + 0] = a.x; v[q * 4 + 1] = a.y;
            v[q * 4 + 2] = a.z; v[q * 4 + 3] = a.w;
        }
    } else {
#pragma unroll
        for (int j = 0; j < 16; ++j)
            v[j] = (base + j < N) ? indeg[base + j] : 0;
    }
#pragma unroll
    for (int j = 0; j < 16; ++j)
        if (base + j < N) dinv[base + j] = rsqrtf((float)(v[j] + 1));

    int sum = 0;
#pragma unroll
    for (int j = 0; j < 16; ++j) { const int tv = v[j]; v[j] = sum; sum += tv; }

    int incl = sum;
#pragma unroll
    for (int off = 1; off < 64; off <<= 1) {
        int tt = __shfl_up(incl, off, 64);
        if ((t & 63) >= off) incl += tt;
    }
    __shared__ int wsum[4];
    if ((t & 63) == 63) wsum[t >> 6] = incl;
    __syncthreads();
    int woff = 0;
#pragma unroll
    for (int w = 0; w < 4; ++w) woff += (w < (t >> 6)) ? wsum[w] : 0;
    const int texcl = woff + incl - sum;

#pragma unroll
    for (int j = 0; j < 16; ++j)
        if (base + j < N) row_ptr[base + j] = texcl + v[j];
    if (t == 255) partials[blockIdx.x] = woff + incl;
}

// Apply block offsets to row_ptr; last block writes row_ptr[N]. (No cursor.)
__global__ __launch_bounds__(256) void k_scan3(const int* __restrict__ partials,
                                               int* __restrict__ row_ptr,
                                               int N, int nblk) {
    int off = 0;
    for (int w = 0; w < (int)blockIdx.x; ++w) off += partials[w];

    const int base = blockIdx.x * SCAN_CHUNK + threadIdx.x * 16;
    if (base + 15 < N) {
        int4* rp = reinterpret_cast<int4*>(row_ptr + base);
#pragma unroll
        for (int q = 0; q < 4; ++q) {
            int4 a = rp[q];
            a.x += off; a.y += off; a.z += off; a.w += off;
            rp[q] = a;
        }
    } else {
#pragma unroll
        for (int j = 0; j < 16; ++j) {
            const int i = base + j;
            if (i < N) row_ptr[i] += off;
        }
    }
    if ((int)blockIdx.x == nblk - 1 && threadIdx.x == 255)
        row_ptr[N] = off + partials[nblk - 1];
}

// MFMA GEMM1, LDS-free (r9, conflict-free): h1b = x @ W1, split precision.
__device__ __forceinline__ void gemm1_mfma(const float* __restrict__ X,
                                           const unsigned short* __restrict__ w1th,
                                           const unsigned short* __restrict__ w1tl,
                                           unsigned short* __restrict__ Y,
                                           int M, int blk) {
    const int tid = threadIdx.x;
    const int wv  = tid >> 6;
    const int ln  = tid & 63;
    const int m16 = ln & 15;
    const int g   = ln >> 4;
    const int arow = blk * 64 + wv * 16 + m16;

    f32x4v acc[8];
#pragma unroll
    for (int n = 0; n < 8; ++n) acc[n] = {0.f, 0.f, 0.f, 0.f};

#pragma unroll
    for (int k0 = 0; k0 < 128; k0 += 32) {
        short8v ah, al;
        if (arow < M) {
            const float4 a0 = *reinterpret_cast<const float4*>(
                X + (size_t)arow * 128 + k0 + g * 8);
            const float4 a1 = *reinterpret_cast<const float4*>(
                X + (size_t)arow * 128 + k0 + g * 8 + 4);
            const float f[8] = {a0.x, a0.y, a0.z, a0.w, a1.x, a1.y, a1.z, a1.w};
#pragma unroll
            for (int e = 0; e < 8; ++e) {
                const unsigned short h = f2bf_rne(f[e]);
                ah[e] = (short)h;
                al[e] = (short)f2bf_rne(f[e] - bf2f(h));
            }
        } else {
#pragma unroll
            for (int e = 0; e < 8; ++e) { ah[e] = 0; al[e] = 0; }
        }

#pragma unroll
        for (int n = 0; n < 8; ++n) {
            const short8v bh = *reinterpret_cast<const short8v*>(
                w1th + (n * 16 + m16) * 128 + k0 + g * 8);
            const short8v bl = *reinterpret_cast<const short8v*>(
                w1tl + (n * 16 + m16) * 128 + k0 + g * 8);
            acc[n] = __builtin_amdgcn_mfma_f32_16x16x32_bf16(ah, bh, acc[n], 0, 0, 0);
            acc[n] = __builtin_amdgcn_mfma_f32_16x16x32_bf16(al, bh, acc[n], 0, 0, 0);
            acc[n] = __builtin_amdgcn_mfma_f32_16x16x32_bf16(ah, bl, acc[n], 0, 0, 0);
        }
    }

#pragma unroll
    for (int r = 0; r < 4; ++r) {
        const int orow = blk * 64 + wv * 16 + g * 4 + r;
        if (orow < M) {
#pragma unroll
            for (int n = 0; n < 8; ++n)
                Y[(size_t)orow * 128 + n * 16 + m16] = f2bf_rne(acc[n][r]);
        }
    }
}

// Dual-role: blocks [0, fillBlocks) = ATOMIC-FREE streaming fill
// (csr[row_ptr[d]+rank[e]] = {src, dinv[src]}); the rest = MFMA gemm1.
__global__ __launch_bounds__(256) void k_fill_gemm1(
    const float* __restrict__ X, const unsigned short* __restrict__ w1th,
    const unsigned short* __restrict__ w1tl, unsigned short* __restrict__ Y,
    int M, int fillBlocks, const int* __restrict__ ei,
    const int* __restrict__ rank, const int* __restrict__ row_ptr,
    const float* __restrict__ dinv, int2* __restrict__ csr, int E) {
    if ((int)blockIdx.x >= fillBlocks) {
        gemm1_mfma(X, w1th, w1tl, Y, M, blockIdx.x - fillBlocks);
        return;
    }
    const bool is64 = probe_is64(ei);
    const int nthr = fillBlocks * 256;
    const int idx  = blockIdx.x * 256 + threadIdx.x;
    for (int e0 = idx * 4; e0 < E; e0 += nthr * 4) {
        const int n = min(4, E - e0);
        int s[4], d[4], rk[4];
        load_idx4(ei, is64, 0,            e0, n, s);
        load_idx4(ei, is64, (long long)E, e0, n, d);
        if (n == 4) {
            const int4 r = *reinterpret_cast<const int4*>(rank + e0);
            rk[0] = r.x; rk[1] = r.y; rk[2] = r.z; rk[3] = r.w;
        } else {
            for (int j = 0; j < n; ++j) rk[j] = rank[e0 + j];
        }
        int pos[4];
        float w[4];
        for (int j = 0; j < n; ++j) pos[j] = row_ptr[d[j]] + rk[j];
        for (int j = 0; j < n; ++j) w[j] = dinv[s[j]];
        for (int j = 0; j < n; ++j)
            csr[pos[j]] = make_int2(s[j], __float_as_int(w[j]));
    }
}

// MFMA GEMM2, LDS-free: h2b = aggb(bf16 exact) @ W2, W2 split.
__global__ __launch_bounds__(256) void k_gemm2_mfma(
    const unsigned short* __restrict__ Xb, const unsigned short* __restrict__ w2th,
    const unsigned short* __restrict__ w2tl, unsigned short* __restrict__ Y, int M) {
    const int tid = threadIdx.x;
    const int wv  = tid >> 6;
    const int ln  = tid & 63;
    const int m16 = ln & 15;
    const int g   = ln >> 4;
    const int arow = blockIdx.x * 64 + wv * 16 + m16;

    f32x4v acc[4];
#pragma unroll
    for (int n = 0; n < 4; ++n) acc[n] = {0.f, 0.f, 0.f, 0.f};

#pragma unroll
    for (int k0 = 0; k0 < 128; k0 += 32) {
        short8v a;
        if (arow < M) {
            a = *reinterpret_cast<const short8v*>(Xb + (size_t)arow * 128 + k0 + g * 8);
        } else {
#pragma unroll
            for (int e = 0; e < 8; ++e) a[e] = 0;
        }
#pragma unroll
        for (int n = 0; n < 4; ++n) {
            const short8v bh = *reinterpret_cast<const short8v*>(
                w2th + (n * 16 + m16) * 128 + k0 + g * 8);
            const short8v bl = *reinterpret_cast<const short8v*>(
                w2tl + (n * 16 + m16) * 128 + k0 + g * 8);
            acc[n] = __builtin_amdgcn_mfma_f32_16x16x32_bf16(a, bh, acc[n], 0, 0, 0);
            acc[n] = __builtin_amdgcn_mfma_f32_16x16x32_bf16(a, bl, acc[n], 0, 0, 0);
        }
    }

#pragma unroll
    for (int r = 0; r < 4; ++r) {
        const int orow = blockIdx.x * 64 + wv * 16 + g * 4 + r;
        if (orow < M) {
#pragma unroll
            for (int n = 0; n < 4; ++n)
                Y[(size_t)orow * 64 + n * 16 + m16] = f2bf_rne(acc[n][r]);
        }
    }
}

// aggb[n](bf16) = relu(b1 + h[n]*dinv[n]^2 + sum_e h[rec.src]*rec.w*dinv[n])
__global__ __launch_bounds__(256) void k_gather_relu(
    const unsigned short* __restrict__ h, const int* __restrict__ row_ptr,
    const int2* __restrict__ csr, const float* __restrict__ dinv,
    const float* __restrict__ b, unsigned short* __restrict__ aggb, int N) {
    constexpr int LPN = HID / 4;   // 32
    const int tid  = blockIdx.x * blockDim.x + threadIdx.x;
    const int node = tid / LPN;
    const int lane = tid % LPN;
    if (node >= N) return;

    const float dn = dinv[node];
    float4 acc = reinterpret_cast<const float4*>(b)[lane];
    {
        const float w = dn * dn;
        const ushort4 v = *reinterpret_cast<const ushort4*>(h + (size_t)node * HID + lane * 4);
        acc.x = fmaf(bf2f(v.x), w, acc.x); acc.y = fmaf(bf2f(v.y), w, acc.y);
        acc.z = fmaf(bf2f(v.z), w, acc.z); acc.w = fmaf(bf2f(v.w), w, acc.w);
    }

    const int e1 = row_ptr[node + 1];
    int e = row_ptr[node];
    for (; e + 1 < e1; e += 2) {
        const int2 r0 = csr[e];
        const int2 r1 = csr[e + 1];
        const float w0 = __int_as_float(r0.y) * dn;
        const float w1 = __int_as_float(r1.y) * dn;
        const ushort4 v0 = *reinterpret_cast<const ushort4*>(h + (size_t)r0.x * HID + lane * 4);
        const ushort4 v1 = *reinterpret_cast<const ushort4*>(h + (size_t)r1.x * HID + lane * 4);
        acc.x = fmaf(bf2f(v0.x), w0, acc.x); acc.y = fmaf(bf2f(v0.y), w0, acc.y);
        acc.z = fmaf(bf2f(v0.z), w0, acc.z); acc.w = fmaf(bf2f(v0.w), w0, acc.w);
        acc.x = fmaf(bf2f(v1.x), w1, acc.x); acc.y = fmaf(bf2f(v1.y), w1, acc.y);
        acc.z = fmaf(bf2f(v1.z), w1, acc.z); acc.w = fmaf(bf2f(v1.w), w1, acc.w);
    }
    if (e < e1) {
        const int2 r0 = csr[e];
        const float w0 = __int_as_float(r0.y) * dn;
        const ushort4 v0 = *reinterpret_cast<const ushort4*>(h + (size_t)r0.x * HID + lane * 4);
        acc.x = fmaf(bf2f(v0.x), w0, acc.x); acc.y = fmaf(bf2f(v0.y), w0, acc.y);
        acc.z = fmaf(bf2f(v0.z), w0, acc.z); acc.w = fmaf(bf2f(v0.w), w0, acc.w);
    }

    ushort4 o;
    o.x = f2bf_rne(fmaxf(acc.x, 0.f));
    o.y = f2bf_rne(fmaxf(acc.y, 0.f));
    o.z = f2bf_rne(fmaxf(acc.z, 0.f));
    o.w = f2bf_rne(fmaxf(acc.w, 0.f));
    *reinterpret_cast<ushort4*>(aggb + (size_t)node * HID + lane * 4) = o;
}

// out[n](f32) = b2 + h[n]*dinv[n]^2 + sum_e h[rec.src]*rec.w*dinv[n]
__global__ __launch_bounds__(256) void k_gather64(
    const unsigned short* __restrict__ h, const int* __restrict__ row_ptr,
    const int2* __restrict__ csr, const float* __restrict__ dinv,
    const float* __restrict__ b, float* __restrict__ out, int N) {
    constexpr int LPN = OUT_CH / 4;   // 16
    const int tid  = blockIdx.x * blockDim.x + threadIdx.x;
    const int node = tid / LPN;
    const int lane = tid % LPN;
    if (node >= N) return;

    const float dn = dinv[node];
    float4 acc = reinterpret_cast<const float4*>(b)[lane];
    {
        const float w = dn * dn;
        const ushort4 v = *reinterpret_cast<const ushort4*>(h + (size_t)node * OUT_CH + lane * 4);
        acc.x = fmaf(bf2f(v.x), w, acc.x); acc.y = fmaf(bf2f(v.y), w, acc.y);
        acc.z = fmaf(bf2f(v.z), w, acc.z); acc.w = fmaf(bf2f(v.w), w, acc.w);
    }

    const int e1 = row_ptr[node + 1];
    int e = row_ptr[node];
    for (; e + 1 < e1; e += 2) {
        const int2 r0 = csr[e];
        const int2 r1 = csr[e + 1];
        const float w0 = __int_as_float(r0.y) * dn;
        const float w1 = __int_as_float(r1.y) * dn;
        const ushort4 v0 = *reinterpret_cast<const ushort4*>(h + (size_t)r0.x * OUT_CH + lane * 4);
        const ushort4 v1 = *reinterpret_cast<const ushort4*>(h + (size_t)r1.x * OUT_CH + lane * 4);
        acc.x = fmaf(bf2f(v0.x), w0, acc.x); acc.y = fmaf(bf2f(v0.y), w0, acc.y);
        acc.z = fmaf(bf2f(v0.z), w0, acc.z); acc.w = fmaf(bf2f(v0.w), w0, acc.w);
        acc.x = fmaf(bf2f(v1.x), w1, acc.x); acc.y = fmaf(bf2f(v1.y), w1, acc.y);
        acc.z = fmaf(bf2f(v1.z), w1, acc.z); acc.w = fmaf(bf2f(v1.w), w1, acc.w);
    }
    if (e < e1) {
        const int2 r0 = csr[e];
        const float w0 = __int_as_float(r0.y) * dn;
        const ushort4 v0 = *reinterpret_cast<const ushort4*>(h + (size_t)r0.x * OUT_CH + lane * 4);
        acc.x = fmaf(bf2f(v0.x), w0, acc.x); acc.y = fmaf(bf2f(v0.y), w0, acc.y);
        acc.z = fmaf(bf2f(v0.z), w0, acc.z); acc.w = fmaf(bf2f(v0.w), w0, acc.w);
    }

    reinterpret_cast<float4*>(out + (size_t)node * OUT_CH)[lane] = acc;
}

extern "C" void kernel_launch(void* const* d_in, const int* in_sizes, int n_in,
                              void* d_out, int out_size, void* d_ws, size_t ws_size,
                              hipStream_t stream) {
    const float* x  = (const float*)d_in[0];
    const int*   ei = (const int*)d_in[1];
    const float* W1 = (const float*)d_in[2];
    const float* b1 = (const float*)d_in[3];
    const float* W2 = (const float*)d_in[4];
    const float* b2 = (const float*)d_in[5];
    float* out = (float*)d_out;

    const int N = in_sizes[0] / IN_CH;   // 50000
    const int E = in_sizes[1] / 2;       // 600000
    const int NBLK = (N + SCAN_CHUNK - 1) / SCAN_CHUNK;   // 13

    char* wsb = (char*)d_ws;
    size_t off = 0;
    auto alloc = [&](size_t bytes) -> void* {
        void* p = wsb + off;
        off += (bytes + 255) & ~(size_t)255;
        return p;
    };
    int*   indeg    = (int*)alloc((size_t)N * sizeof(int));
    int*   rank     = (int*)alloc((size_t)E * sizeof(int));
    int*   partials = (int*)alloc(64 * sizeof(int));
    float* dinv     = (float*)alloc((size_t)N * sizeof(float));
    int*   row_ptr  = (int*)alloc(((size_t)N + 1) * sizeof(int));
    int2*  csr      = (int2*)alloc((size_t)E * sizeof(int2));
    unsigned short* w1th = (unsigned short*)alloc(128 * 128 * sizeof(unsigned short));
    unsigned short* w1tl = (unsigned short*)alloc(128 * 128 * sizeof(unsigned short));
    unsigned short* w2th = (unsigned short*)alloc(64 * 128 * sizeof(unsigned short));
    unsigned short* w2tl = (unsigned short*)alloc(64 * 128 * sizeof(unsigned short));
    unsigned short* h1b  = (unsigned short*)alloc((size_t)N * HID * sizeof(unsigned short));
    unsigned short* aggb = (unsigned short*)alloc((size_t)N * HID * sizeof(unsigned short));
    unsigned short* h2b  = (unsigned short*)alloc((size_t)N * OUT_CH * sizeof(unsigned short));

    auto gs = [](long long n) { return (int)((n + 255) / 256); };

    k_init<<<88, 256, 0, stream>>>(indeg, N, W1, W2, w1th, w1tl, w2th, w2tl);
    k_count_rank<<<gs((E + 3) / 4), 256, 0, stream>>>(ei, indeg, rank, E);
    k_scan1<<<NBLK, 256, 0, stream>>>(indeg, row_ptr, dinv, partials, N);
    k_scan3<<<NBLK, 256, 0, stream>>>(partials, row_ptr, N, NBLK);

    // atomic-free streaming fill (first) || LDS-free MFMA gemm1
    const int fillBlocks = 512;
    const int gemmBlocks = (N + 63) / 64;   // 782
    k_fill_gemm1<<<fillBlocks + gemmBlocks, 256, 0, stream>>>(
        x, w1th, w1tl, h1b, N, fillBlocks, ei, rank, row_ptr, dinv, csr, E);

    k_gather_relu<<<gs((long long)N * (HID / 4)), 256, 0, stream>>>(
        h1b, row_ptr, csr, dinv, b1, aggb, N);

    k_gemm2_mfma<<<(N + 63) / 64, 256, 0, stream>>>(aggb, w2th, w2tl, h2b, N);

    k_gather64<<<gs((long long)N * (OUT_CH / 4)), 256, 0, stream>>>(
        h2b, row_ptr, csr, dinv, b2, out, N);
}

// Round 12
// 154.499 us; speedup vs baseline: 1.3643x; 1.0291x over previous
//
#include <hip/hip_runtime.h>

// GCN 2-layer encoder for MI355X (gfx950) — round 12.
// r11 post-mortem: atomic-free fill didn't move the 46-50us fill||gemm1
// dispatch; 5 rounds of fill variants all land ~46-50 and fill-ALONE was
// never measured. r12 restructures for attribution + overlap:
//   - gemm1 hides under k_count_rank (both only need inputs) -> the fill
//     runs STANDALONE and its true cost shows in the profile.
//   - gather1+ReLU+gemm2 fused properly: 17KB LDS only to transpose the
//     gathered 64x128 bf16 tile into MFMA A-frags; matrix-core GEMM2;
//     aggb round-trip eliminated.
//
// Pipeline (7 dispatches):
//   k_init(zero indeg || split W1,W2) -> k_count_gemm1(count+rank || mfma
//   gemm1) -> k_scan1(+dinv) -> k_scan3 -> k_fill(standalone, atomic-free)
//   -> k_gather_gemm2(h1b -> h2b) -> k_gather64(h2b -> out)

constexpr int IN_CH  = 128;
constexpr int HID    = 128;
constexpr int OUT_CH = 64;
constexpr int SCAN_CHUNK = 4096;

using short8v = __attribute__((ext_vector_type(8))) short;
using f32x4v  = __attribute__((ext_vector_type(4))) float;

__device__ __forceinline__ unsigned short f2bf_rne(float f) {
    unsigned int u = __float_as_uint(f);
    u += 0x7FFFu + ((u >> 16) & 1u);
    return (unsigned short)(u >> 16);
}
__device__ __forceinline__ float bf2f(unsigned short h) {
    return __uint_as_float((unsigned int)h << 16);
}

__device__ __forceinline__ bool probe_is64(const int* __restrict__ ei) {
    const int v = ei[2 * (threadIdx.x & 63) + 1];
    return __ballot(v != 0) == 0ull;
}

__device__ __forceinline__ void load_idx4(const int* __restrict__ ei, bool is64,
                                          long long hb, int e0, int n, int* out) {
    const long long p = hb + e0;
    if (is64) {
        if (n == 4 && ((p & 1) == 0)) {
            const int4 a = *reinterpret_cast<const int4*>(ei + 2 * p);
            const int4 b = *reinterpret_cast<const int4*>(ei + 2 * p + 4);
            out[0] = a.x; out[1] = a.z; out[2] = b.x; out[3] = b.z;
        } else {
            for (int j = 0; j < n; ++j) out[j] = ei[2 * (p + j)];
        }
    } else {
        if (n == 4 && ((p & 3) == 0)) {
            const int4 a = *reinterpret_cast<const int4*>(ei + p);
            out[0] = a.x; out[1] = a.y; out[2] = a.z; out[3] = a.w;
        } else {
            for (int j = 0; j < n; ++j) out[j] = ei[p + j];
        }
    }
}

// 8 bf16 (one uint4) fma into two float4 accumulators.
__device__ __forceinline__ void fma8(float4& a0, float4& a1, uint4 u, float w) {
    a0.x = fmaf(__uint_as_float(u.x << 16), w, a0.x);
    a0.y = fmaf(__uint_as_float(u.x & 0xffff0000u), w, a0.y);
    a0.z = fmaf(__uint_as_float(u.y << 16), w, a0.z);
    a0.w = fmaf(__uint_as_float(u.y & 0xffff0000u), w, a0.w);
    a1.x = fmaf(__uint_as_float(u.z << 16), w, a1.x);
    a1.y = fmaf(__uint_as_float(u.z & 0xffff0000u), w, a1.y);
    a1.z = fmaf(__uint_as_float(u.w << 16), w, a1.z);
    a1.w = fmaf(__uint_as_float(u.w & 0xffff0000u), w, a1.w);
}

// blocks 0..63: zero indeg. 64..79: split W1 (bf16 hi/lo, transposed [n][k]).
// 80..87: split W2.
__global__ __launch_bounds__(256) void k_init(int* __restrict__ indeg, int N,
                                              const float* __restrict__ W1,
                                              const float* __restrict__ W2,
                                              unsigned short* __restrict__ w1th,
                                              unsigned short* __restrict__ w1tl,
                                              unsigned short* __restrict__ w2th,
                                              unsigned short* __restrict__ w2tl) {
    const int b = blockIdx.x;
    if (b < 64) {
        const int i = b * 256 + threadIdx.x;
        const int n4 = N / 4;
        for (int j = i; j < n4; j += 64 * 256)
            reinterpret_cast<int4*>(indeg)[j] = make_int4(0, 0, 0, 0);
        const int tail = n4 * 4 + i;
        if (tail < N) indeg[tail] = 0;
    } else if (b < 80) {
        const int i = (b - 64) * 1024 + threadIdx.x * 4;
        const int n = i >> 7, k = i & 127;
#pragma unroll
        for (int j = 0; j < 4; ++j) {
            const float f = W1[(size_t)(k + j) * HID + n];
            const unsigned short h = f2bf_rne(f);
            w1th[n * 128 + k + j] = h;
            w1tl[n * 128 + k + j] = f2bf_rne(f - bf2f(h));
        }
    } else {
        const int i = (b - 80) * 1024 + threadIdx.x * 4;
        const int n = i >> 7, k = i & 127;
#pragma unroll
        for (int j = 0; j < 4; ++j) {
            const float f = W2[(size_t)(k + j) * OUT_CH + n];
            const unsigned short h = f2bf_rne(f);
            w2th[n * 128 + k + j] = h;
            w2tl[n * 128 + k + j] = f2bf_rne(f - bf2f(h));
        }
    }
}

// MFMA GEMM1, LDS-free (r9/r11, verified numerics): h1b = x @ W1 split-prec.
__device__ __forceinline__ void gemm1_mfma(const float* __restrict__ X,
                                           const unsigned short* __restrict__ w1th,
                                           const unsigned short* __restrict__ w1tl,
                                           unsigned short* __restrict__ Y,
                                           int M, int blk) {
    const int tid = threadIdx.x;
    const int wv  = tid >> 6;
    const int ln  = tid & 63;
    const int m16 = ln & 15;
    const int g   = ln >> 4;
    const int arow = blk * 64 + wv * 16 + m16;

    f32x4v acc[8];
#pragma unroll
    for (int n = 0; n < 8; ++n) acc[n] = {0.f, 0.f, 0.f, 0.f};

#pragma unroll
    for (int k0 = 0; k0 < 128; k0 += 32) {
        short8v ah, al;
        if (arow < M) {
            const float4 a0 = *reinterpret_cast<const float4*>(
                X + (size_t)arow * 128 + k0 + g * 8);
            const float4 a1 = *reinterpret_cast<const float4*>(
                X + (size_t)arow * 128 + k0 + g * 8 + 4);
            const float f[8] = {a0.x, a0.y, a0.z, a0.w, a1.x, a1.y, a1.z, a1.w};
#pragma unroll
            for (int e = 0; e < 8; ++e) {
                const unsigned short h = f2bf_rne(f[e]);
                ah[e] = (short)h;
                al[e] = (short)f2bf_rne(f[e] - bf2f(h));
            }
        } else {
#pragma unroll
            for (int e = 0; e < 8; ++e) { ah[e] = 0; al[e] = 0; }
        }

#pragma unroll
        for (int n = 0; n < 8; ++n) {
            const short8v bh = *reinterpret_cast<const short8v*>(
                w1th + (n * 16 + m16) * 128 + k0 + g * 8);
            const short8v bl = *reinterpret_cast<const short8v*>(
                w1tl + (n * 16 + m16) * 128 + k0 + g * 8);
            acc[n] = __builtin_amdgcn_mfma_f32_16x16x32_bf16(ah, bh, acc[n], 0, 0, 0);
            acc[n] = __builtin_amdgcn_mfma_f32_16x16x32_bf16(al, bh, acc[n], 0, 0, 0);
            acc[n] = __builtin_amdgcn_mfma_f32_16x16x32_bf16(ah, bl, acc[n], 0, 0, 0);
        }
    }

#pragma unroll
    for (int r = 0; r < 4; ++r) {
        const int orow = blk * 64 + wv * 16 + g * 4 + r;
        if (orow < M) {
#pragma unroll
            for (int n = 0; n < 8; ++n)
                Y[(size_t)orow * 128 + n * 16 + m16] = f2bf_rne(acc[n][r]);
        }
    }
}

// Dual-role: blocks [0, countBlocks) = count+rank; rest = MFMA gemm1.
// (gemm1 needs only inputs -> hides under the count instead of the fill.)
__global__ __launch_bounds__(256) void k_count_gemm1(
    const int* __restrict__ ei, int* __restrict__ indeg, int* __restrict__ rank,
    int E, int countBlocks,
    const float* __restrict__ X, const unsigned short* __restrict__ w1th,
    const unsigned short* __restrict__ w1tl, unsigned short* __restrict__ h1b,
    int M) {
    if ((int)blockIdx.x >= countBlocks) {
        gemm1_mfma(X, w1th, w1tl, h1b, M, blockIdx.x - countBlocks);
        return;
    }
    const bool is64 = probe_is64(ei);
    const int idx    = blockIdx.x * 256 + threadIdx.x;
    const int stride = countBlocks * 256;
    for (int e0 = idx * 4; e0 < E; e0 += stride * 4) {
        const int n = min(4, E - e0);
        int d[4];
        load_idx4(ei, is64, (long long)E, e0, n, d);
        if (n == 4) {
            int4 r;
            r.x = atomicAdd(&indeg[d[0]], 1);
            r.y = atomicAdd(&indeg[d[1]], 1);
            r.z = atomicAdd(&indeg[d[2]], 1);
            r.w = atomicAdd(&indeg[d[3]], 1);
            *reinterpret_cast<int4*>(rank + e0) = r;
        } else {
            for (int j = 0; j < n; ++j)
                rank[e0 + j] = atomicAdd(&indeg[d[j]], 1);
        }
    }
}

// Exclusive scan of indeg -> row_ptr; dinv = rsqrt(indeg+1); partials.
__global__ __launch_bounds__(256) void k_scan1(const int* __restrict__ indeg,
                                               int* __restrict__ row_ptr,
                                               float* __restrict__ dinv,
                                               int* __restrict__ partials, int N) {
    const int t    = threadIdx.x;
    const int base = blockIdx.x * SCAN_CHUNK + t * 16;
    int v[16];
    if (base + 15 < N) {
        const int4* p = reinterpret_cast<const int4*>(indeg + base);
#pragma unroll
        for (int q = 0; q < 4; ++q) {
            const int4 a = p[q];
            v[q * 4 + 0] = a.x; v[q * 4 + 1] = a.y;
            v[q * 4 + 2] = a.z; v[q * 4 + 3] = a.w;
        }
    } else {
#pragma unroll
        for (int j = 0; j < 16; ++j)
            v[j] = (base + j < N) ? indeg[base + j] : 0;
    }
#pragma unroll
    for (int j = 0; j < 16; ++j)
        if (base + j < N) dinv[base + j] = rsqrtf((float)(v[j] + 1));

    int sum = 0;
#pragma unroll
    for (int j = 0; j < 16; ++j) { const int tv = v[j]; v[j] = sum; sum += tv; }

    int incl = sum;
#pragma unroll
    for (int off = 1; off < 64; off <<= 1) {
        int tt = __shfl_up(incl, off, 64);
        if ((t & 63) >= off) incl += tt;
    }
    __shared__ int wsum[4];
    if ((t & 63) == 63) wsum[t >> 6] = incl;
    __syncthreads();
    int woff = 0;
#pragma unroll
    for (int w = 0; w < 4; ++w) woff += (w < (t >> 6)) ? wsum[w] : 0;
    const int texcl = woff + incl - sum;

#pragma unroll
    for (int j = 0; j < 16; ++j)
        if (base + j < N) row_ptr[base + j] = texcl + v[j];
    if (t == 255) partials[blockIdx.x] = woff + incl;
}

// Apply block offsets to row_ptr; last block writes row_ptr[N].
__global__ __launch_bounds__(256) void k_scan3(const int* __restrict__ partials,
                                               int* __restrict__ row_ptr,
                                               int N, int nblk) {
    int off = 0;
    for (int w = 0; w < (int)blockIdx.x; ++w) off += partials[w];

    const int base = blockIdx.x * SCAN_CHUNK + threadIdx.x * 16;
    if (base + 15 < N) {
        int4* rp = reinterpret_cast<int4*>(row_ptr + base);
#pragma unroll
        for (int q = 0; q < 4; ++q) {
            int4 a = rp[q];
            a.x += off; a.y += off; a.z += off; a.w += off;
            rp[q] = a;
        }
    } else {
#pragma unroll
        for (int j = 0; j < 16; ++j) {
            const int i = base + j;
            if (i < N) row_ptr[i] += off;
        }
    }
    if ((int)blockIdx.x == nblk - 1 && threadIdx.x == 255)
        row_ptr[N] = off + partials[nblk - 1];
}

// STANDALONE atomic-free fill (attribution): csr[row_ptr[d]+rank[e]] =
// {src, dinv_bits[src]}.
__global__ __launch_bounds__(256) void k_fill(
    const int* __restrict__ ei, const int* __restrict__ rank,
    const int* __restrict__ row_ptr, const float* __restrict__ dinv,
    int2* __restrict__ csr, int E) {
    const bool is64 = probe_is64(ei);
    const int idx    = blockIdx.x * blockDim.x + threadIdx.x;
    const int stride = gridDim.x * blockDim.x;
    for (int e0 = idx * 4; e0 < E; e0 += stride * 4) {
        const int n = min(4, E - e0);
        int s[4], d[4], rk[4];
        load_idx4(ei, is64, 0,            e0, n, s);
        load_idx4(ei, is64, (long long)E, e0, n, d);
        if (n == 4) {
            const int4 r = *reinterpret_cast<const int4*>(rank + e0);
            rk[0] = r.x; rk[1] = r.y; rk[2] = r.z; rk[3] = r.w;
        } else {
            for (int j = 0; j < n; ++j) rk[j] = rank[e0 + j];
        }
        int pos[4];
        float w[4];
        for (int j = 0; j < n; ++j) pos[j] = row_ptr[d[j]] + rk[j];
        for (int j = 0; j < n; ++j) w[j] = dinv[s[j]];
        for (int j = 0; j < n; ++j)
            csr[pos[j]] = make_int2(s[j], __float_as_int(w[j]));
    }
}

// FUSED gather1 + bias + ReLU + MFMA GEMM2 -> h2b (bf16). 64 nodes/block.
// Phase 1: 4 lanes/node x 32 ch register gather (f32 acc), ReLU, bf16 into
//          LDS xs[64][136] (transpose staging for A-frags; ~17.4KB).
// Phase 2: per wave a 16-row A tile; A-frags via ds_read_b128; W2 hi/lo
//          frags from global (L2); 32 MFMAs; store h2b.
__global__ __launch_bounds__(256) void k_gather_gemm2(
    const unsigned short* __restrict__ h1b, const int* __restrict__ row_ptr,
    const int2* __restrict__ csr, const float* __restrict__ dinv,
    const float* __restrict__ b1,
    const unsigned short* __restrict__ w2th, const unsigned short* __restrict__ w2tl,
    unsigned short* __restrict__ h2b, int N) {
    constexpr int XSS = 136;   // bf16 elems/row: 272B, 16B-aligned
    __shared__ __align__(16) unsigned short xs[64 * XSS];

    const int tid  = threadIdx.x;
    const int r    = tid >> 2;       // local node 0..63
    const int lane = tid & 3;        // 32-channel slice
    const int node = blockIdx.x * 64 + r;
    const int c0   = lane * 32;

    float4 acc[8];
    if (node < N) {
#pragma unroll
        for (int q = 0; q < 8; ++q)
            acc[q] = reinterpret_cast<const float4*>(b1 + c0)[q];
        const float dn = dinv[node];
        {
            const float ws = dn * dn;  // self loop
            const uint4* hp = reinterpret_cast<const uint4*>(h1b + (size_t)node * HID + c0);
#pragma unroll
            for (int q = 0; q < 4; ++q) fma8(acc[2 * q], acc[2 * q + 1], hp[q], ws);
        }
        const int e1 = row_ptr[node + 1];
        int e = row_ptr[node];
        for (; e + 1 < e1; e += 2) {
            const int2 r0 = csr[e];
            const int2 r1 = csr[e + 1];
            const float w0 = __int_as_float(r0.y) * dn;
            const float w1 = __int_as_float(r1.y) * dn;
            const uint4* s0 = reinterpret_cast<const uint4*>(h1b + (size_t)r0.x * HID + c0);
            const uint4* s1 = reinterpret_cast<const uint4*>(h1b + (size_t)r1.x * HID + c0);
#pragma unroll
            for (int q = 0; q < 4; ++q) fma8(acc[2 * q], acc[2 * q + 1], s0[q], w0);
#pragma unroll
            for (int q = 0; q < 4; ++q) fma8(acc[2 * q], acc[2 * q + 1], s1[q], w1);
        }
        if (e < e1) {
            const int2 r0 = csr[e];
            const float w0 = __int_as_float(r0.y) * dn;
            const uint4* s0 = reinterpret_cast<const uint4*>(h1b + (size_t)r0.x * HID + c0);
#pragma unroll
            for (int q = 0; q < 4; ++q) fma8(acc[2 * q], acc[2 * q + 1], s0[q], w0);
        }
    } else {
#pragma unroll
        for (int q = 0; q < 8; ++q) acc[q] = make_float4(0.f, 0.f, 0.f, 0.f);
    }

    // ReLU + pack to bf16 into LDS
#pragma unroll
    for (int q = 0; q < 8; ++q) {
        float4 a = acc[q];
        ushort4 o;
        o.x = f2bf_rne(fmaxf(a.x, 0.f));
        o.y = f2bf_rne(fmaxf(a.y, 0.f));
        o.z = f2bf_rne(fmaxf(a.z, 0.f));
        o.w = f2bf_rne(fmaxf(a.w, 0.f));
        *reinterpret_cast<ushort4*>(&xs[r * XSS + c0 + 4 * q]) = o;
    }
    __syncthreads();

    // Phase 2: MFMA xs(64x128) @ W2(128x64), split W2.
    const int wv  = tid >> 6;
    const int ln  = tid & 63;
    const int m16 = ln & 15;
    const int g   = ln >> 4;

    f32x4v acc2[4];
#pragma unroll
    for (int n = 0; n < 4; ++n) acc2[n] = {0.f, 0.f, 0.f, 0.f};

#pragma unroll
    for (int k0 = 0; k0 < 128; k0 += 32) {
        const short8v a = *reinterpret_cast<const short8v*>(
            &xs[(wv * 16 + m16) * XSS + k0 + g * 8]);
#pragma unroll
        for (int n = 0; n < 4; ++n) {
            const short8v bh = *reinterpret_cast<const short8v*>(
                w2th + (n * 16 + m16) * 128 + k0 + g * 8);
            const short8v bl = *reinterpret_cast<const short8v*>(
                w2tl + (n * 16 + m16) * 128 + k0 + g * 8);
            acc2[n] = __builtin_amdgcn_mfma_f32_16x16x32_bf16(a, bh, acc2[n], 0, 0, 0);
            acc2[n] = __builtin_amdgcn_mfma_f32_16x16x32_bf16(a, bl, acc2[n], 0, 0, 0);
        }
    }

#pragma unroll
    for (int rr = 0; rr < 4; ++rr) {
        const int orow = blockIdx.x * 64 + wv * 16 + g * 4 + rr;
        if (orow < N) {
#pragma unroll
            for (int n = 0; n < 4; ++n)
                h2b[(size_t)orow * OUT_CH + n * 16 + m16] = f2bf_rne(acc2[n][rr]);
        }
    }
}

// out[n](f32) = b2 + h[n]*dinv[n]^2 + sum_e h[rec.src]*rec.w*dinv[n]
__global__ __launch_bounds__(256) void k_gather64(
    const unsigned short* __restrict__ h, const int* __restrict__ row_ptr,
    const int2* __restrict__ csr, const float* __restrict__ dinv,
    const float* __restrict__ b, float* __restrict__ out, int N) {
    constexpr int LPN = OUT_CH / 4;   // 16
    const int tid  = blockIdx.x * blockDim.x + threadIdx.x;
    const int node = tid / LPN;
    const int lane = tid % LPN;
    if (node >= N) return;

    const float dn = dinv[node];
    float4 acc = reinterpret_cast<const float4*>(b)[lane];
    {
        const float w = dn * dn;
        const ushort4 v = *reinterpret_cast<const ushort4*>(h + (size_t)node * OUT_CH + lane * 4);
        acc.x = fmaf(bf2f(v.x), w, acc.x); acc.y = fmaf(bf2f(v.y), w, acc.y);
        acc.z = fmaf(bf2f(v.z), w, acc.z); acc.w = fmaf(bf2f(v.w), w, acc.w);
    }

    const int e1 = row_ptr[node + 1];
    int e = row_ptr[node];
    for (; e + 1 < e1; e += 2) {
        const int2 r0 = csr[e];
        const int2 r1 = csr[e + 1];
        const float w0 = __int_as_float(r0.y) * dn;
        const float w1 = __int_as_float(r1.y) * dn;
        const ushort4 v0 = *reinterpret_cast<const ushort4*>(h + (size_t)r0.x * OUT_CH + lane * 4);
        const ushort4 v1 = *reinterpret_cast<const ushort4*>(h + (size_t)r1.x * OUT_CH + lane * 4);
        acc.x = fmaf(bf2f(v0.x), w0, acc.x); acc.y = fmaf(bf2f(v0.y), w0, acc.y);
        acc.z = fmaf(bf2f(v0.z), w0, acc.z); acc.w = fmaf(bf2f(v0.w), w0, acc.w);
        acc.x = fmaf(bf2f(v1.x), w1, acc.x); acc.y = fmaf(bf2f(v1.y), w1, acc.y);
        acc.z = fmaf(bf2f(v1.z), w1, acc.z); acc.w = fmaf(bf2f(v1.w), w1, acc.w);
    }
    if (e < e1) {
        const int2 r0 = csr[e];
        const float w0 = __int_as_float(r0.y) * dn;
        const ushort4 v0 = *reinterpret_cast<const ushort4*>(h + (size_t)r0.x * OUT_CH + lane * 4);
        acc.x = fmaf(bf2f(v0.x), w0, acc.x); acc.y = fmaf(bf2f(v0.y), w0, acc.y);
        acc.z = fmaf(bf2f(v0.z), w0, acc.z); acc.w = fmaf(bf2f(v0.w), w0, acc.w);
    }

    reinterpret_cast<float4*>(out + (size_t)node * OUT_CH)[lane] = acc;
}

extern "C" void kernel_launch(void* const* d_in, const int* in_sizes, int n_in,
                              void* d_out, int out_size, void* d_ws, size_t ws_size,
                              hipStream_t stream) {
    const float* x  = (const float*)d_in[0];
    const int*   ei = (const int*)d_in[1];
    const float* W1 = (const float*)d_in[2];
    const float* b1 = (const float*)d_in[3];
    const float* W2 = (const float*)d_in[4];
    const float* b2 = (const float*)d_in[5];
    float* out = (float*)d_out;

    const int N = in_sizes[0] / IN_CH;   // 50000
    const int E = in_sizes[1] / 2;       // 600000
    const int NBLK = (N + SCAN_CHUNK - 1) / SCAN_CHUNK;   // 13

    char* wsb = (char*)d_ws;
    size_t off = 0;
    auto alloc = [&](size_t bytes) -> void* {
        void* p = wsb + off;
        off += (bytes + 255) & ~(size_t)255;
        return p;
    };
    int*   indeg    = (int*)alloc((size_t)N * sizeof(int));
    int*   rank     = (int*)alloc((size_t)E * sizeof(int));
    int*   partials = (int*)alloc(64 * sizeof(int));
    float* dinv     = (float*)alloc((size_t)N * sizeof(float));
    int*   row_ptr  = (int*)alloc(((size_t)N + 1) * sizeof(int));
    int2*  csr      = (int2*)alloc((size_t)E * sizeof(int2));
    unsigned short* w1th = (unsigned short*)alloc(128 * 128 * sizeof(unsigned short));
    unsigned short* w1tl = (unsigned short*)alloc(128 * 128 * sizeof(unsigned short));
    unsigned short* w2th = (unsigned short*)alloc(64 * 128 * sizeof(unsigned short));
    unsigned short* w2tl = (unsigned short*)alloc(64 * 128 * sizeof(unsigned short));
    unsigned short* h1b  = (unsigned short*)alloc((size_t)N * HID * sizeof(unsigned short));
    unsigned short* h2b  = (unsigned short*)alloc((size_t)N * OUT_CH * sizeof(unsigned short));

    auto gs = [](long long n) { return (int)((n + 255) / 256); };

    k_init<<<88, 256, 0, stream>>>(indeg, N, W1, W2, w1th, w1tl, w2th, w2tl);

    // count+rank (critical path) || MFMA gemm1 (independent)
    const int countBlocks = gs((E + 3) / 4);   // 586
    const int gemmBlocks  = (N + 63) / 64;     // 782
    k_count_gemm1<<<countBlocks + gemmBlocks, 256, 0, stream>>>(
        ei, indeg, rank, E, countBlocks, x, w1th, w1tl, h1b, N);

    k_scan1<<<NBLK, 256, 0, stream>>>(indeg, row_ptr, dinv, partials, N);
    k_scan3<<<NBLK, 256, 0, stream>>>(partials, row_ptr, N, NBLK);

    // standalone atomic-free fill — attribution target
    k_fill<<<1024, 256, 0, stream>>>(ei, rank, row_ptr, dinv, csr, E);

    // fused gather1 + ReLU + MFMA gemm2
    k_gather_gemm2<<<(N + 63) / 64, 256, 0, stream>>>(
        h1b, row_ptr, csr, dinv, b1, w2th, w2tl, h2b, N);

    // final gather -> out (f32)
    k_gather64<<<gs((long long)N * (OUT_CH / 4)), 256, 0, stream>>>(
        h2b, row_ptr, csr, dinv, b2, out, N);
}